// Round 3
// baseline (13.901 us; speedup 1.0000x reference)
//
#include <hip/hip_runtime.h>
#include <math.h>

#define NG 512
#define NV 76800
#define FD 32
#define CAP 256
// grid 80x80x12 voxels, tiles 8x8x4 -> 10x10x3 = 300 tiles

__global__ __launch_bounds__(256) void voxelize_kernel(
    const float* __restrict__ means, const float* __restrict__ opac,
    const float* __restrict__ cov, const float* __restrict__ feats,
    float* __restrict__ out)
{
    __shared__ float4 gp[CAP];          // mx,my,mz,r2
    __shared__ float4 gq[CAP];          // i00,i01,i02,i11
    __shared__ float4 gt[CAP];          // i12,i22,op,-
    __shared__ float  gf[CAP][FD];      // staged feature rows (32 KB)
    __shared__ int    s_n[CAP];
    __shared__ int    s_cnt;

    const int tid  = threadIdx.x;
    const int wv   = tid >> 6;
    const int lane = tid & 63;

    const int b   = blockIdx.x;
    const int tiz = b % 3;
    const int tiy = (b / 3) % 10;
    const int tix = b / 30;

    // tile voxel-center AABB (world units)
    const float xlo = (tix * 8 + 0.5f) * 0.5f - 20.f, xhi = xlo + 3.5f;
    const float ylo = (tiy * 8 + 0.5f) * 0.5f - 20.f, yhi = ylo + 3.5f;
    const float zlo = (tiz * 4 + 0.5f) * 0.5f -  2.f, zhi = zlo + 1.5f;

    if (tid == 0) s_cnt = 0;
    __syncthreads();

    // ---- phase 1: gate 512 gaussians, compact survivors (unordered block-wide list)
    #pragma unroll
    for (int r = 0; r < 2; ++r) {
        const int n = wv * 128 + r * 64 + lane;
        const float a = cov[n*9+0], bb = cov[n*9+1], c = cov[n*9+2];
        const float d = cov[n*9+4], e  = cov[n*9+5], f = cov[n*9+8];
        const float sx = sqrtf(a), sy = sqrtf(d), sz = sqrtf(f);
        const float mx = means[n*3+0], my = means[n*3+1], mz = means[n*3+2];
        const float op = opac[n];
        const bool keep =
            (mx + 3.f*sx > -20.f) && (my + 3.f*sy > -20.f) && (mz + 3.f*sz > -2.f) &&
            (mx - 3.f*sx <  20.f) && (my - 3.f*sy <  20.f) && (mz - 3.f*sz <  4.4f) &&
            (op > 1e-4f);
        const float smax = fmaxf(sx, fmaxf(sy, sz));
        const float r2 = 9.f * smax * smax;
        const float cx = fminf(fmaxf(mx, xlo), xhi) - mx;
        const float cy = fminf(fmaxf(my, ylo), yhi) - my;
        const float cz = fminf(fmaxf(mz, zlo), zhi) - mz;
        const float d2t = cx*cx + cy*cy + cz*cz;
        const bool pred = keep && (d2t < r2);

        const unsigned long long m = __ballot(pred);
        int wofs = 0;
        if (lane == 0) wofs = atomicAdd(&s_cnt, (int)__popcll(m));
        wofs = __shfl(wofs, 0);
        const int pos = wofs + (int)__popcll(m & ((1ull << lane) - 1ull));
        if (pred && pos < CAP) {
            const float det = a*(d*f - e*e) - bb*(bb*f - c*e) + c*(bb*e - c*d);
            const float id = 1.f / det;
            gp[pos] = make_float4(mx, my, mz, r2);
            gq[pos] = make_float4((d*f - e*e) * id,   // i00
                                  (c*e - bb*f) * id,  // i01
                                  (bb*e - c*d) * id,  // i02
                                  (a*f - c*c) * id);  // i11
            gt[pos] = make_float4((bb*c - a*e) * id,  // i12
                                  (a*d - bb*bb) * id, // i22
                                  op, 0.f);
            s_n[pos] = n;
        }
    }
    __syncthreads();
    const int ks = (s_cnt < CAP) ? s_cnt : CAP;

    // ---- phase 1.5: stage survivor feature rows into LDS (coalesced float4)
    for (int it = tid; it < ks * 8; it += 256) {
        const int s = it >> 3, j = it & 7;
        ((float4*)gf[s])[j] = ((const float4*)(feats + (size_t)s_n[s] * FD))[j];
    }
    __syncthreads();

    // ---- phase 2: per-voxel accumulation, all operands in LDS, 1-ahead prefetch
    const int lz = tid & 3;
    const int ly = (tid >> 2) & 7;
    const int lx = tid >> 5;
    const int ix = tix * 8 + lx;
    const int iy = tiy * 8 + ly;
    const int iz = tiz * 4 + lz;
    const float x = (ix + 0.5f) * 0.5f - 20.f;
    const float y = (iy + 0.5f) * 0.5f - 20.f;
    const float z = (iz + 0.5f) * 0.5f -  2.f;

    float dens = 0.f;
    float4 acc[8];
    #pragma unroll
    for (int j = 0; j < 8; ++j) acc[j] = make_float4(0.f, 0.f, 0.f, 0.f);

    float4 p = make_float4(0,0,0,-1.f), q = p, t = p;
    if (ks > 0) { p = gp[0]; q = gq[0]; t = gt[0]; }

    for (int i = 0; i < ks; ++i) {
        const int ip = (i + 1 < ks) ? i + 1 : i;
        const float4 pn = gp[ip], qn = gq[ip], tn = gt[ip];

        const float dx = p.x - x, dy = p.y - y, dz = p.z - z;
        const float d2 = dx*dx + dy*dy + dz*dz;
        if (d2 < p.w) {
            const float maha = q.x*dx*dx + q.w*dy*dy + t.y*dz*dz
                             + 2.f*(q.y*dx*dy + q.z*dx*dz + t.x*dy*dz);
            const float w = t.z * __expf(-0.5f * maha);
            dens += w;
            const float4* fp = (const float4*)gf[i];
            #pragma unroll
            for (int j = 0; j < 8; ++j) {
                const float4 f4 = fp[j];
                acc[j].x += w * f4.x; acc[j].y += w * f4.y;
                acc[j].z += w * f4.z; acc[j].w += w * f4.w;
            }
        }
        p = pn; q = qn; t = tn;
    }

    const int v = (ix * 80 + iy) * 12 + iz;
    out[v] = dens;
    const float inv = 1.f / fmaxf(dens, 1e-6f);
    float4* fo = (float4*)(out + NV + (size_t)v * FD);
    #pragma unroll
    for (int j = 0; j < 8; ++j) {
        float4 rr;
        rr.x = acc[j].x * inv; rr.y = acc[j].y * inv;
        rr.z = acc[j].z * inv; rr.w = acc[j].w * inv;
        fo[j] = rr;
    }
}

extern "C" void kernel_launch(void* const* d_in, const int* in_sizes, int n_in,
                              void* d_out, int out_size, void* d_ws, size_t ws_size,
                              hipStream_t stream) {
    const float* means = (const float*)d_in[0];
    const float* opac  = (const float*)d_in[1];
    const float* cov   = (const float*)d_in[2];
    const float* feats = (const float*)d_in[3];
    float* out = (float*)d_out;
    voxelize_kernel<<<300, 256, 0, stream>>>(means, opac, cov, feats, out);
}